// Round 15
// baseline (73.524 us; speedup 1.0000x reference)
//
#include <hip/hip_runtime.h>
#include <math.h>

#define N 8192
#define C 64
#define K 16
#define NB 8
#define QB 8
#define LNODES 8
#define HS 72   // bf16 row stride (elements) for LDS tiles: 144B, 16B-aligned, bank-uniform

typedef unsigned long long u64;
typedef unsigned int u32;

typedef float  f32x4v  __attribute__((ext_vector_type(4)));
typedef __bf16 bf16x8  __attribute__((ext_vector_type(8)));

__device__ __forceinline__ unsigned short bfr(float f) {   // f32 -> bf16 RTNE
    u32 u = __float_as_uint(f);
    return (unsigned short)((u + 0x7fffu + ((u >> 16) & 1u)) >> 16);
}

// ---------------- fused prep: pos4 (|p|^2 in .w) + bf16-transposed edge weights ----------------
__global__ __launch_bounds__(256) void prep_all(const float* __restrict__ pos,
                                                float4* __restrict__ pos4,
                                                const float* __restrict__ p2w,
                                                const float* __restrict__ a1w,
                                                const float* __restrict__ a2w,
                                                unsigned short* __restrict__ wT) {
    const int id = blockIdx.x * 256 + threadIdx.x;
    if (id < N) {
        const float px = pos[3*id], py = pos[3*id+1], pz = pos[3*id+2];
        pos4[id] = make_float4(px, py, pz, fmaf(px, px, fmaf(py, py, pz * pz)));
    } else {
        const int t = id - N;
        if (t < 3 * C * C) {
            const int m = t >> 12, r = t & (C*C - 1);
            const int e = r >> 6, c = r & 63;
            const float* w = (m == 0) ? p2w : (m == 1) ? a1w : a2w;
            wT[m * C * HS + c * HS + e] = bfr(w[r]);
        }
    }
}

// ---------------- Kernel 1: KNN, block-per-8-queries, sparse rescan, 9-round threshold ------
// Pass 1: thread t streams 16 disjoint candidates, proxy pr = |pj|^2 - 2*dot per query;
// minima -> LDS. Wave w: per-lane 2nd-smallest of its 8 thread-minima, pop 9 rounds ->
// >=9 cleared lanes x >=2 threads = >=18 disjoint-subset candidates <= T (>=17 incl self)
// => thr conservative. List threads with smin<=thr; rescan only their subsets (bit-identical
// proxy test); exact (f64,idx) rank, self removed by index. Fallback: serial exact.
__global__ __launch_bounds__(512) void knn_kernel(const float4* __restrict__ pos4,
                                                  int* __restrict__ idx_out) {
    __shared__ float          smin[QB][512];   // 16 KB
    __shared__ unsigned short s_tl[QB][96];    // 1.5 KB
    __shared__ int            s_tlc[QB];
    __shared__ int            s_buf[QB][128];  // 4 KB
    __shared__ double         s_d[QB][128];    // 8 KB
    __shared__ int            s_cnt[QB];
    __shared__ double         s_fd[QB][K];     // fallback (pathological only)
    __shared__ int            s_fi[QB][K];

    const int tid  = threadIdx.x;
    const int w    = tid >> 6;
    const int lane = tid & 63;
    const int i0   = blockIdx.x * QB;

    if (tid < QB) { s_cnt[tid] = 0; s_tlc[tid] = 0; }

    float qx[QB], qy[QB], qz[QB];
    #pragma unroll
    for (int q = 0; q < QB; ++q) {
        const float4 p = pos4[i0 + q];
        qx[q] = p.x; qy[q] = p.y; qz[q] = p.z;
    }

    // ---- pass 1: per-thread proxy-min per query over 16 disjoint candidates (self incl.) ----
    float mn[QB];
    #pragma unroll
    for (int q = 0; q < QB; ++q) mn[q] = INFINITY;
    #pragma unroll 4
    for (int s = 0; s < 16; ++s) {
        const int j = (s << 9) + tid;
        const float4 pj = pos4[j];
        #pragma unroll
        for (int q = 0; q < QB; ++q) {
            const float dot = fmaf(qx[q], pj.x, fmaf(qy[q], pj.y, qz[q] * pj.z));
            const float pr  = fmaf(-2.0f, dot, pj.w);
            mn[q] = fminf(mn[q], pr);
        }
    }
    #pragma unroll
    for (int q = 0; q < QB; ++q) smin[q][tid] = mn[q];
    __syncthreads();   // the only block barrier; everything below is wave-private

    // ---- wave w: per-lane 2nd-min of its 8 thread-minima; T = 9-round evict-min ----
    float thw;
    {
        float vv[8];
        #pragma unroll
        for (int k = 0; k < 8; ++k) vv[k] = smin[w][lane + 64*k];
        float m1 = INFINITY, m2 = INFINITY;
        #pragma unroll
        for (int k = 0; k < 8; ++k) {
            const float val = vv[k];
            const bool lt = val < m1;
            m2 = lt ? m1 : fminf(m2, val);
            m1 = lt ? val : m1;
        }
        float cur = m2, T = 0.0f;
        for (int r = 0; r < 9; ++r) {   // 9 rounds; dup-pops only enlarge T = conservative
            float m = cur;
            #pragma unroll
            for (int off = 32; off; off >>= 1) m = fminf(m, __shfl_xor(m, off, 64));
            T = m;
            cur = (cur == m) ? INFINITY : cur;
        }
        thw = T + 1e-3f + 4e-6f * fabsf(T);   // proxy f32-error margin
        #pragma unroll
        for (int k = 0; k < 8; ++k) {
            if (vv[k] <= thw) {
                const int slot = atomicAdd(&s_tlc[w], 1);
                if (slot < 96) s_tl[w][slot] = (unsigned short)(lane + 64*k);
            }
        }
    }

    // ---- sparse rescan: only listed threads' subsets (bit-identical proxy test) ----
    {
        const int lc_raw = s_tlc[w];
        const int lc = lc_raw < 96 ? lc_raw : 96;
        const float qwx = qx[w], qwy = qy[w], qwz = qz[w];
        for (int p = lane; p < lc * 16; p += 64) {
            const int t = s_tl[w][p >> 4];
            const int s = p & 15;
            const int j = (s << 9) + t;
            const float4 pj = pos4[j];
            const float dot = fmaf(qwx, pj.x, fmaf(qwy, pj.y, qwz * pj.z));
            const float pr  = fmaf(-2.0f, dot, pj.w);
            if (pr <= thw) {
                const int slot = atomicAdd(&s_cnt[w], 1);
                if (slot < 128) s_buf[w][slot] = j;
            }
        }
    }

    // ---- exact (f64 dist, idx) rank for query w; self removed by index ----
    {
        const int q  = w;
        const int iq = i0 + q;
        const int cno = s_cnt[q];
        if (cno <= 128 && s_tlc[q] <= 96) {
            const int cn = cno;
            const double dqx = (double)qx[q], dqy = (double)qy[q], dqz = (double)qz[q];
            for (int sl = lane; sl < cn; sl += 64) {
                const int jj = s_buf[q][sl];
                const float4 pj = pos4[jj];
                const double dx = dqx - (double)pj.x;
                const double dy = dqy - (double)pj.y;
                const double dz = dqz - (double)pj.z;
                s_d[q][sl] = dx*dx + dy*dy + dz*dz;
            }
            for (int sl = lane; sl < cn; sl += 64) {
                const int jj = s_buf[q][sl];
                if (jj == iq) continue;
                const double dj = s_d[q][sl];
                int r = 0;
                for (int e = 0; e < cn; ++e) {
                    const double de = s_d[q][e];
                    const int    je = s_buf[q][e];
                    r += (de < dj || (de == dj && je < jj)) ? 1 : 0;
                }
                const int selfb = (dj > 0.0 || (dj == 0.0 && iq < jj)) ? 1 : 0;
                const int rr = r - selfb;
                if (rr < K) idx_out[iq*K + rr] = jj;
            }
        } else {
            if (lane == 0) {   // pathological safety net: serial exact top-16 over all N
                for (int kk = 0; kk < K; ++kk) { s_fd[w][kk] = 1e300; s_fi[w][kk] = 0x7fffffff; }
                const double dqx = (double)qx[q], dqy = (double)qy[q], dqz = (double)qz[q];
                for (int j = 0; j < N; ++j) {
                    if (j == iq) continue;
                    const float4 pj = pos4[j];
                    const double dx = dqx - (double)pj.x;
                    const double dy = dqy - (double)pj.y;
                    const double dz = dqz - (double)pj.z;
                    const double dd = dx*dx + dy*dy + dz*dz;
                    if (dd < s_fd[w][K-1] || (dd == s_fd[w][K-1] && j < s_fi[w][K-1])) {
                        int p = K - 1;
                        while (p > 0 && (dd < s_fd[w][p-1] || (dd == s_fd[w][p-1] && j < s_fi[w][p-1]))) {
                            s_fd[w][p] = s_fd[w][p-1]; s_fi[w][p] = s_fi[w][p-1]; --p;
                        }
                        s_fd[w][p] = dd; s_fi[w][p] = j;
                    }
                }
                for (int kk = 0; kk < K; ++kk) idx_out[iq*K + kk] = s_fi[w][kk];
            }
        }
    }
}

// ---------------- Kernel 2: projections, weights in registers, 8 nodes/block (R10) ----------
__global__ __launch_bounds__(192) void lin3_kernel(const float* __restrict__ x,
    const float* __restrict__ w_src, const float* __restrict__ w_dst,
    const float* __restrict__ w_lin, const float* __restrict__ b_lin,
    float* __restrict__ a_dst, float* __restrict__ a_src, float* __restrict__ v) {
    __shared__ float xr[LNODES][C];
    const int n0  = blockIdx.x * LNODES;
    const int tid = threadIdx.x;
    const int cc  = tid & 63;
    const int m   = tid >> 6;

    const float* w = (m == 0) ? w_dst : (m == 1) ? w_src : w_lin;
    float wreg[C];
    #pragma unroll
    for (int k = 0; k < C; ++k) wreg[k] = w[k*C + cc];

    for (int t = tid; t < LNODES*C; t += 192) xr[t >> 6][t & 63] = x[n0*C + t];
    __syncthreads();

    const float binit = (m == 2) ? b_lin[cc] : 0.0f;
    float* o = (m == 0) ? a_dst : (m == 1) ? a_src : v;
    for (int nn = 0; nn < LNODES; ++nn) {
        float acc = binit;
        const float4* xv = (const float4*)xr[nn];
        #pragma unroll
        for (int k4 = 0; k4 < 16; ++k4) {
            const float4 xx = xv[k4];
            acc = fmaf(xx.x, wreg[4*k4+0], acc);
            acc = fmaf(xx.y, wreg[4*k4+1], acc);
            acc = fmaf(xx.z, wreg[4*k4+2], acc);
            acc = fmaf(xx.w, wreg[4*k4+3], acc);
        }
        o[(n0 + nn)*C + cc] = acc;
    }
}

// ---- 16x64 @ 64x64 via 8 MFMA (A: wave-private bf16 tile, B: transposed bf16 weights) ----
__device__ __forceinline__ void mm16x64(const unsigned short* Hb, const unsigned short* wT,
                                        int c0, int sg, f32x4v acc[4]) {
    const bf16x8 a0 = *reinterpret_cast<const bf16x8*>(Hb + c0*HS + sg*8);
    const bf16x8 a1 = *reinterpret_cast<const bf16x8*>(Hb + c0*HS + 32 + sg*8);
    #pragma unroll
    for (int q = 0; q < 4; ++q) {
        const unsigned short* wr = wT + (q*16 + c0)*HS + sg*8;
        const bf16x8 b0 = *reinterpret_cast<const bf16x8*>(wr);
        const bf16x8 b1 = *reinterpret_cast<const bf16x8*>(wr + 32);
        acc[q] = __builtin_amdgcn_mfma_f32_16x16x32_bf16(a0, b0, acc[q], 0, 0, 0);
        acc[q] = __builtin_amdgcn_mfma_f32_16x16x32_bf16(a1, b1, acc[q], 0, 0, 0);
    }
}

// ---------------- Kernel 3: edge pipeline, wave-per-node, MFMA (R10 verbatim) ----------------
__global__ __launch_bounds__(512, 4) void edge_kernel(
    const float* __restrict__ x, const float* __restrict__ pos,
    const int* __restrict__ nidx,
    const float* __restrict__ a_dst, const float* __restrict__ a_src, const float* __restrict__ v,
    const unsigned short* __restrict__ wTg,
    const float* __restrict__ p1w, const float* __restrict__ p1b,
    const float* __restrict__ p1g, const float* __restrict__ p1bt,
    const float* __restrict__ p2b,
    const float* __restrict__ a1b, const float* __restrict__ a1g, const float* __restrict__ a1bt,
    const float* __restrict__ a2b,
    const float* __restrict__ uw, const float* __restrict__ ub,
    float* __restrict__ out) {

    __shared__ __align__(16) unsigned short sWT[3 * C * HS];
    __shared__ __align__(16) float          uwf[C * C];
    __shared__ __align__(16) unsigned short sHb[NB * K * HS];
    __shared__ __align__(16) float4         sMisc4[NB * 16];
    __shared__ int                          sIdx[NB * K];

    const int tid  = threadIdx.x;
    const int w    = tid >> 6;
    const int lane = tid & 63;
    const int c0   = tid & 15;
    const int sg   = (tid >> 4) & 3;
    const int n    = blockIdx.x * NB + w;

    unsigned short* Hlb = sHb + w * (K * HS);
    float4*         Ml4 = sMisc4 + w * 16;
    float*          Mlf = (float*)Ml4;
    int*            Il  = sIdx + w * K;

    {
        const float4* s4 = (const float4*)wTg;          // 1728 float4
        float4* d4 = (float4*)sWT;
        #pragma unroll
        for (int q = 0; q < 4; ++q) {
            const int e = tid + q*512;
            if (e < 1728) d4[e] = s4[e];
        }
        float4* du = (float4*)uwf;
        const float4* su = (const float4*)uw;
        du[tid] = su[tid]; du[tid + 512] = su[tid + 512];
    }
    if (lane < K) {
        const int j = nidx[n*K + lane];
        Il[lane] = j;
        float4 r;
        r.x = pos[3*n]   - pos[3*j];
        r.y = pos[3*n+1] - pos[3*j+1];
        r.z = pos[3*n+2] - pos[3*j+2];
        r.w = 0.0f;
        Ml4[lane] = r;
    }
    __syncthreads();   // the ONLY block barrier

    int c4[4];
    #pragma unroll
    for (int q = 0; q < 4; ++q) c4[q] = q*16 + c0;

    {
        float W0[4], W1[4], W2[4], B_[4], G_[4], BT[4];
        #pragma unroll
        for (int q = 0; q < 4; ++q) {
            const int cc = c4[q];
            W0[q] = p1w[cc]; W1[q] = p1w[C + cc]; W2[q] = p1w[2*C + cc];
            B_[q] = p1b[cc]; G_[q] = p1g[cc];     BT[q] = p1bt[cc];
        }
        #pragma unroll
        for (int r = 0; r < 4; ++r) {
            const float4 rr = Ml4[sg*4 + r];
            #pragma unroll
            for (int q = 0; q < 4; ++q) {
                float t = fmaf(rr.x, W0[q], fmaf(rr.y, W1[q], fmaf(rr.z, W2[q], B_[q])));
                t = fmaxf(fmaf(G_[q], t, BT[q]), 0.0f);
                Hlb[(sg*4 + r)*HS + c4[q]] = bfr(t);
            }
        }
    }

    f32x4v acc[4], del[4];
    #pragma unroll
    for (int q = 0; q < 4; ++q) { const float b_ = p2b[c4[q]]; acc[q] = (f32x4v){b_, b_, b_, b_}; }
    mm16x64(Hlb, sWT, c0, sg, acc);
    #pragma unroll
    for (int q = 0; q < 4; ++q) del[q] = acc[q];

    int jr[4];
    #pragma unroll
    for (int r = 0; r < 4; ++r) jr[r] = Il[sg*4 + r];
    float adstv[4];
    #pragma unroll
    for (int q = 0; q < 4; ++q) adstv[q] = a_dst[n*C + c4[q]];

    #pragma unroll
    for (int r = 0; r < 4; ++r) {
        #pragma unroll
        for (int q = 0; q < 4; ++q) {
            const float t = adstv[q] - a_src[jr[r]*C + c4[q]] + acc[q][r];
            Hlb[(sg*4 + r)*HS + c4[q]] = bfr(t);
        }
    }

    #pragma unroll
    for (int q = 0; q < 4; ++q) { const float b_ = a1b[c4[q]]; acc[q] = (f32x4v){b_, b_, b_, b_}; }
    mm16x64(Hlb, sWT + C*HS, c0, sg, acc);
    #pragma unroll
    for (int q = 0; q < 4; ++q) {
        const float g_ = a1g[c4[q]], bt_ = a1bt[c4[q]];
        #pragma unroll
        for (int r = 0; r < 4; ++r) {
            const float h2 = fmaxf(fmaf(g_, acc[q][r], bt_), 0.0f);
            Hlb[(sg*4 + r)*HS + c4[q]] = bfr(h2);
        }
    }

    #pragma unroll
    for (int q = 0; q < 4; ++q) { const float b_ = a2b[c4[q]]; acc[q] = (f32x4v){b_, b_, b_, b_}; }
    mm16x64(Hlb, sWT + 2*C*HS, c0, sg, acc);

    float o_[4];
    #pragma unroll
    for (int q = 0; q < 4; ++q) {
        float vgq[4];
        #pragma unroll
        for (int r = 0; r < 4; ++r) vgq[r] = v[jr[r]*C + c4[q]];
        float lm = fmaxf(fmaxf(acc[q][0], acc[q][1]), fmaxf(acc[q][2], acc[q][3]));
        lm = fmaxf(lm, __shfl_xor(lm, 16, 64));
        lm = fmaxf(lm, __shfl_xor(lm, 32, 64));
        float ls = 0.0f, lo = 0.0f;
        #pragma unroll
        for (int r = 0; r < 4; ++r) {
            const float e_ = __expf(acc[q][r] - lm);
            ls += e_;
            lo = fmaf(e_, vgq[r] + del[q][r], lo);
        }
        ls += __shfl_xor(ls, 16, 64); ls += __shfl_xor(ls, 32, 64);
        lo += __shfl_xor(lo, 16, 64); lo += __shfl_xor(lo, 32, 64);
        o_[q] = lo / ls;
    }
    if (sg == 0) {
        #pragma unroll
        for (int q = 0; q < 4; ++q) Mlf[c4[q]] = o_[q];
    }

    float facc = ub[lane] + x[n*C + lane];
    #pragma unroll 4
    for (int e4 = 0; e4 < 16; ++e4) {
        const float4 g4 = Ml4[e4];
        facc = fmaf(g4.x, uwf[(e4*4+0)*C + lane], facc);
        facc = fmaf(g4.y, uwf[(e4*4+1)*C + lane], facc);
        facc = fmaf(g4.z, uwf[(e4*4+2)*C + lane], facc);
        facc = fmaf(g4.w, uwf[(e4*4+3)*C + lane], facc);
    }
    out[n*C + lane] = facc;
}

extern "C" void kernel_launch(void* const* d_in, const int* in_sizes, int n_in,
                              void* d_out, int out_size, void* d_ws, size_t ws_size,
                              hipStream_t stream) {
    const float* x     = (const float*)d_in[0];
    const float* pos   = (const float*)d_in[1];
    const float* w_src = (const float*)d_in[2];
    const float* w_dst = (const float*)d_in[3];
    const float* w_lin = (const float*)d_in[4];
    const float* b_lin = (const float*)d_in[5];
    const float* p1w   = (const float*)d_in[6];
    const float* p1b   = (const float*)d_in[7];
    const float* p1g   = (const float*)d_in[8];
    const float* p1bt  = (const float*)d_in[9];
    const float* p2w   = (const float*)d_in[10];
    const float* p2b   = (const float*)d_in[11];
    const float* a1w   = (const float*)d_in[12];
    const float* a1b   = (const float*)d_in[13];
    const float* a1g   = (const float*)d_in[14];
    const float* a1bt  = (const float*)d_in[15];
    const float* a2w   = (const float*)d_in[16];
    const float* a2b   = (const float*)d_in[17];
    const float* uw    = (const float*)d_in[18];
    const float* ub    = (const float*)d_in[19];
    float* out = (float*)d_out;

    char* ws    = (char*)d_ws;
    int*    idx  = (int*)ws;                                    // N*K ints
    float*  adst = (float*)(ws + (size_t)N*K*sizeof(int));
    float*  asrc = adst + (size_t)N*C;
    float*  vv   = asrc + (size_t)N*C;
    float4* pos4 = (float4*)(vv + (size_t)N*C);                 // N float4
    unsigned short* wTg = (unsigned short*)(pos4 + N);          // 3*C*HS bf16

    prep_all<<<(N + 3*C*C + 255)/256, 256, 0, stream>>>(pos, pos4, p2w, a1w, a2w, wTg);
    knn_kernel<<<N/QB, 512, 0, stream>>>(pos4, idx);
    lin3_kernel<<<N/LNODES, 192, 0, stream>>>(x, w_src, w_dst, w_lin, b_lin, adst, asrc, vv);
    edge_kernel<<<N/NB, 512, 0, stream>>>(x, pos, idx, adst, asrc, vv, wTg,
        p1w, p1b, p1g, p1bt, p2b, a1b, a1g, a1bt, a2b, uw, ub, out);
}

// Round 16
// 60.654 us; speedup vs baseline: 1.2122x; 1.2122x over previous
//
#include <hip/hip_runtime.h>
#include <math.h>

#define N 8192
#define C 64
#define K 16
#define NB 8
#define QB 8
#define LNODES 8
#define HS 72   // bf16 row stride (elements) for LDS tiles: 144B, 16B-aligned, bank-uniform

typedef unsigned long long u64;
typedef unsigned int u32;

typedef float  f32x4v  __attribute__((ext_vector_type(4)));
typedef __bf16 bf16x8  __attribute__((ext_vector_type(8)));

__device__ __forceinline__ unsigned short bfr(float f) {   // f32 -> bf16 RTNE
    u32 u = __float_as_uint(f);
    return (unsigned short)((u + 0x7fffu + ((u >> 16) & 1u)) >> 16);
}

// ---------------- fused prep: pos4 (|p|^2 in .w) + bf16-transposed edge weights ----------------
__global__ __launch_bounds__(256) void prep_all(const float* __restrict__ pos,
                                                float4* __restrict__ pos4,
                                                const float* __restrict__ p2w,
                                                const float* __restrict__ a1w,
                                                const float* __restrict__ a2w,
                                                unsigned short* __restrict__ wT) {
    const int id = blockIdx.x * 256 + threadIdx.x;
    if (id < N) {
        const float px = pos[3*id], py = pos[3*id+1], pz = pos[3*id+2];
        pos4[id] = make_float4(px, py, pz, fmaf(px, px, fmaf(py, py, pz * pz)));
    } else {
        const int t = id - N;
        if (t < 3 * C * C) {
            const int m = t >> 12, r = t & (C*C - 1);
            const int e = r >> 6, c = r & 63;
            const float* w = (m == 0) ? p2w : (m == 1) ? a1w : a2w;
            wT[m * C * HS + c * HS + e] = bfr(w[r]);
        }
    }
}

// ---------------- Kernel 1: KNN, block-per-8-queries, sparse rescan (R10 verbatim) ----------
// Pass 1: thread t streams 16 disjoint candidates (j = s*512+t), proxy pr = |pj|^2-2*dot
// per query; minima -> LDS. Wave w (query w): T = 17th-smallest lane-min (17 popped lanes =
// 17 disjoint subsets => coverage); thr = T + margin. List threads with smin<=thr (~20);
// rescan ONLY their subsets (bit-identical proxy test) -> collected = {pr<=thr} exactly.
// Exact (f64,idx) rank over collected, self removed by index. Fallback: serial exact.
__global__ __launch_bounds__(512) void knn_kernel(const float4* __restrict__ pos4,
                                                  int* __restrict__ idx_out) {
    __shared__ float          smin[QB][512];   // 16 KB
    __shared__ float          sthr[QB];
    __shared__ unsigned short s_tl[QB][64];    // candidate-owning thread list (1 KB)
    __shared__ int            s_tlc[QB];
    __shared__ int            s_buf[QB][96];   // 3 KB
    __shared__ double         s_d[QB][96];     // 6 KB
    __shared__ int            s_cnt[QB];
    __shared__ double         s_fd[QB][K];     // fallback (pathological only)
    __shared__ int            s_fi[QB][K];

    const int tid  = threadIdx.x;
    const int w    = tid >> 6;
    const int lane = tid & 63;
    const int i0   = blockIdx.x * QB;

    if (tid < QB) { s_cnt[tid] = 0; s_tlc[tid] = 0; }

    float qx[QB], qy[QB], qz[QB];
    #pragma unroll
    for (int q = 0; q < QB; ++q) {
        const float4 p = pos4[i0 + q];
        qx[q] = p.x; qy[q] = p.y; qz[q] = p.z;
    }

    // ---- pass 1: per-thread proxy-min per query over 16 disjoint candidates ----
    float mn[QB];
    #pragma unroll
    for (int q = 0; q < QB; ++q) mn[q] = INFINITY;
    #pragma unroll 4
    for (int s = 0; s < 16; ++s) {
        const int j = (s << 9) + tid;
        const float4 pj = pos4[j];
        #pragma unroll
        for (int q = 0; q < QB; ++q) {
            const float dot = fmaf(qx[q], pj.x, fmaf(qy[q], pj.y, qz[q] * pj.z));
            const float pr  = fmaf(-2.0f, dot, pj.w);
            mn[q] = fminf(mn[q], pr);
        }
    }
    #pragma unroll
    for (int q = 0; q < QB; ++q) smin[q][tid] = mn[q];
    __syncthreads();   // the only block barrier; everything below is wave-private

    // ---- wave w: T = 17th-smallest lane-min; list threads with smin <= thr ----
    float thw;
    {
        float v[8];
        #pragma unroll
        for (int k = 0; k < 8; ++k) v[k] = smin[w][lane + 64*k];
        float ml = fminf(fminf(fminf(v[0], v[1]), fminf(v[2], v[3])),
                         fminf(fminf(v[4], v[5]), fminf(v[6], v[7])));
        float cur = ml, T = 0.0f;
        for (int r = 0; r < K + 1; ++r) {   // 17 rounds; dup-pops only enlarge T
            float m = cur;
            #pragma unroll
            for (int off = 32; off; off >>= 1) m = fminf(m, __shfl_xor(m, off, 64));
            T = m;
            cur = (cur == m) ? INFINITY : cur;
        }
        thw = T + 1e-3f + 4e-6f * fabsf(T);   // proxy f32-error margin
        if (lane == 0) sthr[w] = thw;
        #pragma unroll
        for (int k = 0; k < 8; ++k) {
            if (v[k] <= thw) {
                const int slot = atomicAdd(&s_tlc[w], 1);
                if (slot < 64) s_tl[w][slot] = (unsigned short)(lane + 64*k);
            }
        }
    }

    // ---- sparse rescan: only listed threads' subsets (bit-identical proxy test) ----
    {
        const int lc_raw = s_tlc[w];
        const int lc = lc_raw < 64 ? lc_raw : 64;
        const float qwx = qx[w], qwy = qy[w], qwz = qz[w];
        for (int p = lane; p < lc * 16; p += 64) {
            const int t = s_tl[w][p >> 4];
            const int s = p & 15;
            const int j = (s << 9) + t;
            const float4 pj = pos4[j];
            const float dot = fmaf(qwx, pj.x, fmaf(qwy, pj.y, qwz * pj.z));
            const float pr  = fmaf(-2.0f, dot, pj.w);
            if (pr <= thw) {
                const int slot = atomicAdd(&s_cnt[w], 1);
                if (slot < 96) s_buf[w][slot] = j;
            }
        }
    }

    // ---- exact (f64 dist, idx) rank for query w; self removed by index ----
    {
        const int q  = w;
        const int iq = i0 + q;
        const int cno = s_cnt[q];
        if (cno <= 96 && s_tlc[q] <= 64) {
            const int cn = cno;
            const double dqx = (double)qx[q], dqy = (double)qy[q], dqz = (double)qz[q];
            for (int sl = lane; sl < cn; sl += 64) {
                const int jj = s_buf[q][sl];
                const float4 pj = pos4[jj];
                const double dx = dqx - (double)pj.x;
                const double dy = dqy - (double)pj.y;
                const double dz = dqz - (double)pj.z;
                s_d[q][sl] = dx*dx + dy*dy + dz*dz;
            }
            for (int sl = lane; sl < cn; sl += 64) {
                const int jj = s_buf[q][sl];
                if (jj == iq) continue;
                const double dj = s_d[q][sl];
                int r = 0;
                for (int e = 0; e < cn; ++e) {
                    const double de = s_d[q][e];
                    const int    je = s_buf[q][e];
                    r += (de < dj || (de == dj && je < jj)) ? 1 : 0;
                }
                const int selfb = (dj > 0.0 || (dj == 0.0 && iq < jj)) ? 1 : 0;
                const int rr = r - selfb;
                if (rr < K) idx_out[iq*K + rr] = jj;
            }
        } else {
            if (lane == 0) {
                for (int kk = 0; kk < K; ++kk) { s_fd[w][kk] = 1e300; s_fi[w][kk] = 0x7fffffff; }
                const double dqx = (double)qx[q], dqy = (double)qy[q], dqz = (double)qz[q];
                for (int j = 0; j < N; ++j) {
                    if (j == iq) continue;
                    const float4 pj = pos4[j];
                    const double dx = dqx - (double)pj.x;
                    const double dy = dqy - (double)pj.y;
                    const double dz = dqz - (double)pj.z;
                    const double dd = dx*dx + dy*dy + dz*dz;
                    if (dd < s_fd[w][K-1] || (dd == s_fd[w][K-1] && j < s_fi[w][K-1])) {
                        int p = K - 1;
                        while (p > 0 && (dd < s_fd[w][p-1] || (dd == s_fd[w][p-1] && j < s_fi[w][p-1]))) {
                            s_fd[w][p] = s_fd[w][p-1]; s_fi[w][p] = s_fi[w][p-1]; --p;
                        }
                        s_fd[w][p] = dd; s_fi[w][p] = j;
                    }
                }
                for (int kk = 0; kk < K; ++kk) idx_out[iq*K + kk] = s_fi[w][kk];
            }
        }
    }
}

// ---------------- Kernel 2: projections, weights in registers, 8 nodes/block (R10) ----------
__global__ __launch_bounds__(192) void lin3_kernel(const float* __restrict__ x,
    const float* __restrict__ w_src, const float* __restrict__ w_dst,
    const float* __restrict__ w_lin, const float* __restrict__ b_lin,
    float* __restrict__ a_dst, float* __restrict__ a_src, float* __restrict__ v) {
    __shared__ float xr[LNODES][C];
    const int n0  = blockIdx.x * LNODES;
    const int tid = threadIdx.x;
    const int cc  = tid & 63;
    const int m   = tid >> 6;

    const float* w = (m == 0) ? w_dst : (m == 1) ? w_src : w_lin;
    float wreg[C];
    #pragma unroll
    for (int k = 0; k < C; ++k) wreg[k] = w[k*C + cc];

    for (int t = tid; t < LNODES*C; t += 192) xr[t >> 6][t & 63] = x[n0*C + t];
    __syncthreads();

    const float binit = (m == 2) ? b_lin[cc] : 0.0f;
    float* o = (m == 0) ? a_dst : (m == 1) ? a_src : v;
    for (int nn = 0; nn < LNODES; ++nn) {
        float acc = binit;
        const float4* xv = (const float4*)xr[nn];
        #pragma unroll
        for (int k4 = 0; k4 < 16; ++k4) {
            const float4 xx = xv[k4];
            acc = fmaf(xx.x, wreg[4*k4+0], acc);
            acc = fmaf(xx.y, wreg[4*k4+1], acc);
            acc = fmaf(xx.z, wreg[4*k4+2], acc);
            acc = fmaf(xx.w, wreg[4*k4+3], acc);
        }
        o[(n0 + nn)*C + cc] = acc;
    }
}

// ---- 16x64 @ 64x64 via 8 MFMA (A: wave-private bf16 tile, B: transposed bf16 weights) ----
__device__ __forceinline__ void mm16x64(const unsigned short* Hb, const unsigned short* wT,
                                        int c0, int sg, f32x4v acc[4]) {
    const bf16x8 a0 = *reinterpret_cast<const bf16x8*>(Hb + c0*HS + sg*8);
    const bf16x8 a1 = *reinterpret_cast<const bf16x8*>(Hb + c0*HS + 32 + sg*8);
    #pragma unroll
    for (int q = 0; q < 4; ++q) {
        const unsigned short* wr = wT + (q*16 + c0)*HS + sg*8;
        const bf16x8 b0 = *reinterpret_cast<const bf16x8*>(wr);
        const bf16x8 b1 = *reinterpret_cast<const bf16x8*>(wr + 32);
        acc[q] = __builtin_amdgcn_mfma_f32_16x16x32_bf16(a0, b0, acc[q], 0, 0, 0);
        acc[q] = __builtin_amdgcn_mfma_f32_16x16x32_bf16(a1, b1, acc[q], 0, 0, 0);
    }
}

// ---------------- Kernel 3: edge pipeline, wave-per-node, MFMA (R10 verbatim) ----------------
__global__ __launch_bounds__(512, 4) void edge_kernel(
    const float* __restrict__ x, const float* __restrict__ pos,
    const int* __restrict__ nidx,
    const float* __restrict__ a_dst, const float* __restrict__ a_src, const float* __restrict__ v,
    const unsigned short* __restrict__ wTg,
    const float* __restrict__ p1w, const float* __restrict__ p1b,
    const float* __restrict__ p1g, const float* __restrict__ p1bt,
    const float* __restrict__ p2b,
    const float* __restrict__ a1b, const float* __restrict__ a1g, const float* __restrict__ a1bt,
    const float* __restrict__ a2b,
    const float* __restrict__ uw, const float* __restrict__ ub,
    float* __restrict__ out) {

    __shared__ __align__(16) unsigned short sWT[3 * C * HS];
    __shared__ __align__(16) float          uwf[C * C];
    __shared__ __align__(16) unsigned short sHb[NB * K * HS];
    __shared__ __align__(16) float4         sMisc4[NB * 16];
    __shared__ int                          sIdx[NB * K];

    const int tid  = threadIdx.x;
    const int w    = tid >> 6;
    const int lane = tid & 63;
    const int c0   = tid & 15;
    const int sg   = (tid >> 4) & 3;
    const int n    = blockIdx.x * NB + w;

    unsigned short* Hlb = sHb + w * (K * HS);
    float4*         Ml4 = sMisc4 + w * 16;
    float*          Mlf = (float*)Ml4;
    int*            Il  = sIdx + w * K;

    {
        const float4* s4 = (const float4*)wTg;          // 1728 float4
        float4* d4 = (float4*)sWT;
        #pragma unroll
        for (int q = 0; q < 4; ++q) {
            const int e = tid + q*512;
            if (e < 1728) d4[e] = s4[e];
        }
        float4* du = (float4*)uwf;
        const float4* su = (const float4*)uw;
        du[tid] = su[tid]; du[tid + 512] = su[tid + 512];
    }
    if (lane < K) {
        const int j = nidx[n*K + lane];
        Il[lane] = j;
        float4 r;
        r.x = pos[3*n]   - pos[3*j];
        r.y = pos[3*n+1] - pos[3*j+1];
        r.z = pos[3*n+2] - pos[3*j+2];
        r.w = 0.0f;
        Ml4[lane] = r;
    }
    __syncthreads();   // the ONLY block barrier

    int c4[4];
    #pragma unroll
    for (int q = 0; q < 4; ++q) c4[q] = q*16 + c0;

    {
        float W0[4], W1[4], W2[4], B_[4], G_[4], BT[4];
        #pragma unroll
        for (int q = 0; q < 4; ++q) {
            const int cc = c4[q];
            W0[q] = p1w[cc]; W1[q] = p1w[C + cc]; W2[q] = p1w[2*C + cc];
            B_[q] = p1b[cc]; G_[q] = p1g[cc];     BT[q] = p1bt[cc];
        }
        #pragma unroll
        for (int r = 0; r < 4; ++r) {
            const float4 rr = Ml4[sg*4 + r];
            #pragma unroll
            for (int q = 0; q < 4; ++q) {
                float t = fmaf(rr.x, W0[q], fmaf(rr.y, W1[q], fmaf(rr.z, W2[q], B_[q])));
                t = fmaxf(fmaf(G_[q], t, BT[q]), 0.0f);
                Hlb[(sg*4 + r)*HS + c4[q]] = bfr(t);
            }
        }
    }

    f32x4v acc[4], del[4];
    #pragma unroll
    for (int q = 0; q < 4; ++q) { const float b_ = p2b[c4[q]]; acc[q] = (f32x4v){b_, b_, b_, b_}; }
    mm16x64(Hlb, sWT, c0, sg, acc);
    #pragma unroll
    for (int q = 0; q < 4; ++q) del[q] = acc[q];

    int jr[4];
    #pragma unroll
    for (int r = 0; r < 4; ++r) jr[r] = Il[sg*4 + r];
    float adstv[4];
    #pragma unroll
    for (int q = 0; q < 4; ++q) adstv[q] = a_dst[n*C + c4[q]];

    #pragma unroll
    for (int r = 0; r < 4; ++r) {
        #pragma unroll
        for (int q = 0; q < 4; ++q) {
            const float t = adstv[q] - a_src[jr[r]*C + c4[q]] + acc[q][r];
            Hlb[(sg*4 + r)*HS + c4[q]] = bfr(t);
        }
    }

    #pragma unroll
    for (int q = 0; q < 4; ++q) { const float b_ = a1b[c4[q]]; acc[q] = (f32x4v){b_, b_, b_, b_}; }
    mm16x64(Hlb, sWT + C*HS, c0, sg, acc);
    #pragma unroll
    for (int q = 0; q < 4; ++q) {
        const float g_ = a1g[c4[q]], bt_ = a1bt[c4[q]];
        #pragma unroll
        for (int r = 0; r < 4; ++r) {
            const float h2 = fmaxf(fmaf(g_, acc[q][r], bt_), 0.0f);
            Hlb[(sg*4 + r)*HS + c4[q]] = bfr(h2);
        }
    }

    #pragma unroll
    for (int q = 0; q < 4; ++q) { const float b_ = a2b[c4[q]]; acc[q] = (f32x4v){b_, b_, b_, b_}; }
    mm16x64(Hlb, sWT + 2*C*HS, c0, sg, acc);

    float o_[4];
    #pragma unroll
    for (int q = 0; q < 4; ++q) {
        float vgq[4];
        #pragma unroll
        for (int r = 0; r < 4; ++r) vgq[r] = v[jr[r]*C + c4[q]];
        float lm = fmaxf(fmaxf(acc[q][0], acc[q][1]), fmaxf(acc[q][2], acc[q][3]));
        lm = fmaxf(lm, __shfl_xor(lm, 16, 64));
        lm = fmaxf(lm, __shfl_xor(lm, 32, 64));
        float ls = 0.0f, lo = 0.0f;
        #pragma unroll
        for (int r = 0; r < 4; ++r) {
            const float e_ = __expf(acc[q][r] - lm);
            ls += e_;
            lo = fmaf(e_, vgq[r] + del[q][r], lo);
        }
        ls += __shfl_xor(ls, 16, 64); ls += __shfl_xor(ls, 32, 64);
        lo += __shfl_xor(lo, 16, 64); lo += __shfl_xor(lo, 32, 64);
        o_[q] = lo / ls;
    }
    if (sg == 0) {
        #pragma unroll
        for (int q = 0; q < 4; ++q) Mlf[c4[q]] = o_[q];
    }

    float facc = ub[lane] + x[n*C + lane];
    #pragma unroll 4
    for (int e4 = 0; e4 < 16; ++e4) {
        const float4 g4 = Ml4[e4];
        facc = fmaf(g4.x, uwf[(e4*4+0)*C + lane], facc);
        facc = fmaf(g4.y, uwf[(e4*4+1)*C + lane], facc);
        facc = fmaf(g4.z, uwf[(e4*4+2)*C + lane], facc);
        facc = fmaf(g4.w, uwf[(e4*4+3)*C + lane], facc);
    }
    out[n*C + lane] = facc;
}

extern "C" void kernel_launch(void* const* d_in, const int* in_sizes, int n_in,
                              void* d_out, int out_size, void* d_ws, size_t ws_size,
                              hipStream_t stream) {
    const float* x     = (const float*)d_in[0];
    const float* pos   = (const float*)d_in[1];
    const float* w_src = (const float*)d_in[2];
    const float* w_dst = (const float*)d_in[3];
    const float* w_lin = (const float*)d_in[4];
    const float* b_lin = (const float*)d_in[5];
    const float* p1w   = (const float*)d_in[6];
    const float* p1b   = (const float*)d_in[7];
    const float* p1g   = (const float*)d_in[8];
    const float* p1bt  = (const float*)d_in[9];
    const float* p2w   = (const float*)d_in[10];
    const float* p2b   = (const float*)d_in[11];
    const float* a1w   = (const float*)d_in[12];
    const float* a1b   = (const float*)d_in[13];
    const float* a1g   = (const float*)d_in[14];
    const float* a1bt  = (const float*)d_in[15];
    const float* a2w   = (const float*)d_in[16];
    const float* a2b   = (const float*)d_in[17];
    const float* uw    = (const float*)d_in[18];
    const float* ub    = (const float*)d_in[19];
    float* out = (float*)d_out;

    char* ws    = (char*)d_ws;
    int*    idx  = (int*)ws;                                    // N*K ints
    float*  adst = (float*)(ws + (size_t)N*K*sizeof(int));
    float*  asrc = adst + (size_t)N*C;
    float*  vv   = asrc + (size_t)N*C;
    float4* pos4 = (float4*)(vv + (size_t)N*C);                 // N float4
    unsigned short* wTg = (unsigned short*)(pos4 + N);          // 3*C*HS bf16

    prep_all<<<(N + 3*C*C + 255)/256, 256, 0, stream>>>(pos, pos4, p2w, a1w, a2w, wTg);
    knn_kernel<<<N/QB, 512, 0, stream>>>(pos4, idx);
    lin3_kernel<<<N/LNODES, 192, 0, stream>>>(x, w_src, w_dst, w_lin, b_lin, adst, asrc, vv);
    edge_kernel<<<N/NB, 512, 0, stream>>>(x, pos, idx, adst, asrc, vv, wTg,
        p1w, p1b, p1g, p1bt, p2b, a1b, a1g, a1bt, a2b, uw, ub, out);
}